// Round 7
// baseline (269.716 us; speedup 1.0000x reference)
//
#include <hip/hip_runtime.h>

typedef _Float16 f16;
typedef f16 f16x8 __attribute__((ext_vector_type(8)));
typedef f16 f16x4 __attribute__((ext_vector_type(4)));
typedef f16 f16x2 __attribute__((ext_vector_type(2)));
typedef float f32x4 __attribute__((ext_vector_type(4)));
typedef unsigned int u32;

#define MFMA16(a, b, c) __builtin_amdgcn_mfma_f32_16x16x32_f16(a, b, c, 0, 0, 0)

#define BATCH 4
#define NHEADS 8
#define HDIM 64
#define SEQ 2048
#define DIN 512
#define DOUT 512
#define LOG2E 1.44269504f
#define C1 0.18033688f  // 0.125 * log2(e), folded into Q at qkv epilogue

__device__ __forceinline__ void gl_lds16(const void* g, const void* l) {
  __builtin_amdgcn_global_load_lds(
      (const __attribute__((address_space(1))) u32*)g,
      (__attribute__((address_space(3))) u32*)l, 16, 0, 0);
}

__device__ __forceinline__ float fexp2(float x) {
  float r;
  asm("v_exp_f32 %0, %1" : "=v"(r) : "v"(x));
  return r;
}

__device__ __forceinline__ f16x2 pk2(float a, float b) {
  return __builtin_bit_cast(f16x2, __builtin_amdgcn_cvt_pkrtz(a, b));
}

__device__ __forceinline__ f16x4 pk4(float a, float b, float c, float d) {
  f16x2 u0 = pk2(a, b), u1 = pk2(c, d);
  f16x4 r;
  r[0] = u0[0]; r[1] = u0[1]; r[2] = u1[0]; r[3] = u1[1];
  return r;
}

// ---------------------------------------------------------------------------
// prep_w: transpose+cvt weights w[k][n] fp32 -> wT[n][k] f16.
// ---------------------------------------------------------------------------
__global__ __launch_bounds__(256) void prep_w(
    const float* __restrict__ wq, const float* __restrict__ wk,
    const float* __restrict__ wv, f16* __restrict__ wT) {
  __shared__ float tile[64][65];
  const float* w = blockIdx.z == 0 ? wq : (blockIdx.z == 1 ? wk : wv);
  f16* out = wT + (size_t)blockIdx.z * DIN * DOUT;
  int k0 = blockIdx.x * 64, n0 = blockIdx.y * 64;
  int t = threadIdx.x;
  int c = t & 63, rb = t >> 6;
#pragma unroll
  for (int ph = 0; ph < 16; ++ph) {
    int r = ph * 4 + rb;
    tile[r][c] = w[(size_t)(k0 + r) * DOUT + n0 + c];
  }
  __syncthreads();
#pragma unroll
  for (int ph = 0; ph < 16; ++ph) {
    int n = ph * 4 + rb;
    out[(size_t)(n0 + n) * DIN + k0 + c] = (f16)tile[c][n];
  }
}

// ---------------------------------------------------------------------------
// qkv_gemm: x(8192x512 f32) @ wT -> Q,K f16 [B,H,S,64]; V^T f16 [B,H,64,S].
// grid (256,1,3): m = bx&63, n = bx>>6 (n-partners share an XCD's L2).
// R7 pipeline: B double-buffered DMA + A register prefetch, both issued
// AFTER the second barrier so their latency overlaps the MFMA phase and is
// drained for free at the next iteration's first barrier.
// Epilogue: R6-verbatim direct f16x4 stores (verified).
// ---------------------------------------------------------------------------
__global__ __launch_bounds__(256, 3) void qkv_gemm(
    const float* __restrict__ xq, const float* __restrict__ xk,
    const float* __restrict__ xv, const f16* __restrict__ wT,
    f16* __restrict__ Qo, f16* __restrict__ Ko, f16* __restrict__ Vt) {
  __shared__ __attribute__((aligned(16))) f16 smem[24576];  // 48 KB
  f16* As = smem;           // 128x64
  f16* Bs0 = smem + 8192;   // 128x64
  f16* Bs1 = smem + 16384;  // 128x64

  int gemm = blockIdx.z;
  const float* x = gemm == 0 ? xq : (gemm == 1 ? xk : xv);
  const f16* wt = wT + (size_t)gemm * DIN * DOUT;
  int bx = blockIdx.x;
  int m0 = (bx & 63) * 128, n0 = (bx >> 6) * 128;
  int t = threadIdx.x, w = t >> 6, lane = t & 63;
  int lr = lane & 15, lq = lane >> 4;
  int wm = (w >> 1) * 64, wn = (w & 1) * 64;

  // A staging (fp32 -> f16 through regs): 16 threads/row, 8 row-phases.
  int tr = t >> 4, tc = t & 15;
  const float* xg = x + (size_t)(m0 + tr) * DIN + tc * 4;
  int aw[8];
#pragma unroll
  for (int ph = 0; ph < 8; ++ph) {
    int r = tr + 16 * ph;
    int phys = (tc >> 1) ^ (r & 7);
    aw[ph] = r * 64 + phys * 8 + (tc & 1) * 4;
  }

  // B staging via DMA: regions of 8 rows x 128B, XOR chunk swizzle.
  int srow = lane >> 3;
  int schunk = (lane & 7) ^ srow;
  const f16* gb[4];
  int lbo[4];
#pragma unroll
  for (int j = 0; j < 4; ++j) {
    int br = w * 32 + j * 8;
    gb[j] = wt + (size_t)(n0 + br + srow) * DIN + schunk * 8;
    lbo[j] = __builtin_amdgcn_readfirstlane(br * 64);
  }
  int xo0 = ((0 * 4 + lq) ^ (lr & 7)) * 8;
  int xo1 = ((1 * 4 + lq) ^ (lr & 7)) * 8;

  f32x4 zero = {0.f, 0.f, 0.f, 0.f};
  f32x4 acc[4][4];
#pragma unroll
  for (int i = 0; i < 4; ++i)
#pragma unroll
    for (int j = 0; j < 4; ++j) acc[i][j] = zero;

  // prologue: DMA B(0) into Bs0, load A(0) into regs
  float4 ar[8];
#pragma unroll
  for (int j = 0; j < 4; ++j) gl_lds16(gb[j], Bs0 + lbo[j]);
#pragma unroll
  for (int ph = 0; ph < 8; ++ph)
    ar[ph] = *(const float4*)(xg + (size_t)ph * 16 * DIN);

  for (int it = 0; it < 8; ++it) {
    f16* Bc = (it & 1) ? Bs1 : Bs0;
    f16* Bn = (it & 1) ? Bs0 : Bs1;
    __syncthreads();  // drains B-DMA(it) and A-loads(it)
#pragma unroll
    for (int ph = 0; ph < 8; ++ph)
      *(f16x4*)&As[aw[ph]] = pk4(ar[ph].x, ar[ph].y, ar[ph].z, ar[ph].w);
    __syncthreads();  // As visible to all waves
    if (it < 7) {
      int k1 = (it + 1) * 64;
#pragma unroll
      for (int j = 0; j < 4; ++j) gl_lds16(gb[j] + k1, Bn + lbo[j]);
#pragma unroll
      for (int ph = 0; ph < 8; ++ph)
        ar[ph] = *(const float4*)(xg + (size_t)ph * 16 * DIN + k1);
    }
#pragma unroll
    for (int c = 0; c < 2; ++c) {
      int xo = c ? xo1 : xo0;
      f16x8 xf[4], wf[4];
#pragma unroll
      for (int i = 0; i < 4; ++i)
        xf[i] = *(const f16x8*)&As[(wm + i * 16 + lr) * 64 + xo];
#pragma unroll
      for (int i = 0; i < 4; ++i)
        wf[i] = *(const f16x8*)&Bc[(wn + i * 16 + lr) * 64 + xo];
      if (gemm == 2) {
#pragma unroll
        for (int i = 0; i < 4; ++i)
#pragma unroll
          for (int j = 0; j < 4; ++j)
            acc[i][j] = MFMA16(xf[i], wf[j], acc[i][j]);
      } else {
#pragma unroll
        for (int i = 0; i < 4; ++i)
#pragma unroll
          for (int j = 0; j < 4; ++j)
            acc[i][j] = MFMA16(wf[i], xf[j], acc[i][j]);
      }
    }
  }

  if (gemm == 2) {
    // D[m=s][n=d], regs = 4 consecutive s -> f16x4 along s in V^T[d][s]
#pragma unroll
    for (int i = 0; i < 4; ++i) {
#pragma unroll
      for (int j = 0; j < 4; ++j) {
        int m = m0 + wm + i * 16 + lq * 4;
        int n = n0 + wn + j * 16 + lr;
        int b = m >> 11, s = m & 2047;
        int h = n >> 6, d = n & 63;
        *(f16x4*)&Vt[(((size_t)b * NHEADS + h) * HDIM + d) * SEQ + s] =
            pk4(acc[i][j][0], acc[i][j][1], acc[i][j][2], acc[i][j][3]);
      }
    }
  } else {
    // swapped: D[m=d][n=s], regs = 4 consecutive d -> f16x4 along d
    f16* O = gemm == 0 ? Qo : Ko;
    float sc = gemm == 0 ? C1 : 1.0f;
#pragma unroll
    for (int i = 0; i < 4; ++i) {
#pragma unroll
      for (int j = 0; j < 4; ++j) {
        int sg = m0 + wm + j * 16 + lr;
        int nd = n0 + wn + i * 16 + lq * 4;
        int b = sg >> 11, s = sg & 2047;
        int h = nd >> 6, d = nd & 63;
        *(f16x4*)&O[(((size_t)b * NHEADS + h) * SEQ + s) * HDIM + d] =
            pk4(acc[i][j][0] * sc, acc[i][j][1] * sc, acc[i][j][2] * sc,
                acc[i][j][3] * sc);
      }
    }
  }
}

// ---------------------------------------------------------------------------
// flash_attn (R6-verbatim, verified): S^T = K.Q^T.  Q-tile 128 (32/wave as
// 2x16 strips, registers), K-tile 128.  No online max; exp2 domain (Q
// pre-scaled by C1, mask folded via fmaf).  grid(bh=32, qt=16).
// ---------------------------------------------------------------------------
__global__ __launch_bounds__(256, 2) void flash_attn(
    const f16* __restrict__ Q, const f16* __restrict__ K,
    const f16* __restrict__ Vt, const float* __restrict__ mask,
    float* __restrict__ out) {
  __shared__ __attribute__((aligned(16))) f16 Ks[128 * 64];   // [k][d] swizzled
  __shared__ __attribute__((aligned(16))) f16 Vs[64 * 128];   // [d][k] swizzled
  __shared__ __attribute__((aligned(16))) f16 Ps[128 * 136];  // [q][k] padded

  int bh = blockIdx.x, q0 = blockIdx.y * 128;
  int b = bh >> 3, h = bh & 7;
  int t = threadIdx.x, w = t >> 6, lane = t & 63;
  int lr = lane & 15, lq = lane >> 4;

  const f16* Qg = Q + (size_t)bh * SEQ * HDIM;
  const f16* Kg = K + (size_t)bh * SEQ * HDIM;
  const f16* Vg = Vt + (size_t)bh * HDIM * SEQ;
  const float* mg = mask + (size_t)b * SEQ;

  // Q fragments in registers: wave rows w*32 + u*16 + lr
  f16x8 qf[2][2];
#pragma unroll
  for (int u = 0; u < 2; ++u)
#pragma unroll
    for (int c = 0; c < 2; ++c)
      qf[u][c] = *(const f16x8*)(Qg +
                                 (size_t)(q0 + w * 32 + u * 16 + lr) * HDIM +
                                 c * 32 + lq * 8);

  // K staging: regions of 8 rows x 128B
  int krow = lane >> 3;
  int kchunk = (lane & 7) ^ krow;
  const f16* gk[4];
  const f16* gv[4];
  const f16* lk[4];
  const f16* lv[4];
#pragma unroll
  for (int j = 0; j < 4; ++j) {
    int kbr = w * 32 + j * 8;
    gk[j] = Kg + (size_t)(kbr + krow) * HDIM + kchunk * 8;
    lk[j] = &Ks[__builtin_amdgcn_readfirstlane(kbr * 64)];
    int vbr = w * 16 + j * 4;
    int vchunk = (lane & 15) ^ (j * 4 + lq);
    gv[j] = Vg + (size_t)(vbr + lq) * SEQ + vchunk * 8;
    lv[j] = &Vs[__builtin_amdgcn_readfirstlane(vbr * 128)];
  }
  int xk0 = ((0 * 4 + lq) ^ (lr & 7)) * 8;
  int xk1 = ((1 * 4 + lq) ^ (lr & 7)) * 8;

  f32x4 zero = {0.f, 0.f, 0.f, 0.f};
  f32x4 acc[2][4];
#pragma unroll
  for (int u = 0; u < 2; ++u)
#pragma unroll
    for (int i = 0; i < 4; ++i) acc[u][i] = zero;
  float lsum[2] = {0.f, 0.f};

  for (int k0 = 0; k0 < SEQ; k0 += 128) {
    __syncthreads();
#pragma unroll
    for (int j = 0; j < 4; ++j) {
      gl_lds16(gk[j] + (size_t)k0 * HDIM, lk[j]);
      gl_lds16(gv[j] + k0, lv[j]);
    }
    __syncthreads();

    // ---- S^T = K Q^T : per strip u, D[m=k][n=q]; q=lane&15, k=lq*4+reg
    f32x4 s[2][8];
#pragma unroll
    for (int nt = 0; nt < 8; ++nt) {
      f16x8 kf0 = *(const f16x8*)&Ks[(nt * 16 + lr) * 64 + xk0];
      f16x8 kf1 = *(const f16x8*)&Ks[(nt * 16 + lr) * 64 + xk1];
      s[0][nt] = MFMA16(kf0, qf[0][0], zero);
      s[0][nt] = MFMA16(kf1, qf[0][1], s[0][nt]);
      s[1][nt] = MFMA16(kf0, qf[1][0], zero);
      s[1][nt] = MFMA16(kf1, qf[1][1], s[1][nt]);
    }

    // ---- p = exp2(s + mask*log2e); accumulate l per lane; pack -> Ps
#pragma unroll
    for (int nt = 0; nt < 8; ++nt) {
      float4 mk = *(const float4*)(mg + k0 + nt * 16 + lq * 4);
#pragma unroll
      for (int u = 0; u < 2; ++u) {
        float p0 = fexp2(fmaf(mk.x, LOG2E, s[u][nt][0]));
        float p1 = fexp2(fmaf(mk.y, LOG2E, s[u][nt][1]));
        float p2 = fexp2(fmaf(mk.z, LOG2E, s[u][nt][2]));
        float p3 = fexp2(fmaf(mk.w, LOG2E, s[u][nt][3]));
        lsum[u] += (p0 + p1) + (p2 + p3);
        *(f16x4*)&Ps[(w * 32 + u * 16 + lr) * 136 + nt * 16 + lq * 4] =
            pk4(p0, p1, p2, p3);
      }
    }

    // ---- O += P V : ap per strip (own rows), bv shared across strips
#pragma unroll
    for (int ks = 0; ks < 4; ++ks) {
      f16x8 ap0 = *(const f16x8*)&Ps[(w * 32 + lr) * 136 + ks * 32 + lq * 8];
      f16x8 ap1 =
          *(const f16x8*)&Ps[(w * 32 + 16 + lr) * 136 + ks * 32 + lq * 8];
#pragma unroll
      for (int dt = 0; dt < 4; ++dt) {
        f16x8 bv = *(const f16x8*)&Vs[(dt * 16 + lr) * 128 +
                                      (((ks * 4 + lq) ^ lr) * 8)];
        acc[0][dt] = MFMA16(ap0, bv, acc[0][dt]);
        acc[1][dt] = MFMA16(ap1, bv, acc[1][dt]);
      }
    }
  }

  // epilogue: l reduction + normalize + store
#pragma unroll
  for (int u = 0; u < 2; ++u) {
    float l = lsum[u];
    l += __shfl_xor(l, 16);
    l += __shfl_xor(l, 32);
    float inv = 1.f / l;
    float iv[4];
#pragma unroll
    for (int r = 0; r < 4; ++r) iv[r] = __shfl(inv, lq * 4 + r);
#pragma unroll
    for (int dt = 0; dt < 4; ++dt) {
#pragma unroll
      for (int r = 0; r < 4; ++r) {
        int q = q0 + w * 32 + u * 16 + lq * 4 + r;
        int d = h * HDIM + dt * 16 + lr;
        out[((size_t)b * SEQ + q) * DOUT + d] = acc[u][dt][r] * iv[r];
      }
    }
  }
}

// ---------------------------------------------------------------------------
extern "C" void kernel_launch(void* const* d_in, const int* in_sizes, int n_in,
                              void* d_out, int out_size, void* d_ws,
                              size_t ws_size, hipStream_t stream) {
  const float* key = (const float*)d_in[0];
  const float* key_mask = (const float*)d_in[1];
  const float* query = (const float*)d_in[2];
  const float* value = (const float*)d_in[3];
  const float* wq = (const float*)d_in[4];
  const float* wk = (const float*)d_in[5];
  const float* wv = (const float*)d_in[6];
  float* out = (float*)d_out;

  char* ws = (char*)d_ws;
  f16* Qws = (f16*)(ws);              //  8.39 MB
  f16* Kws = (f16*)(ws + 8388608);    //  8.39 MB
  f16* Vtws = (f16*)(ws + 16777216);  //  8.39 MB
  f16* wT = (f16*)(ws + 25165824);    //  1.57 MB (total ~26.7 MB)

  prep_w<<<dim3(8, 8, 3), 256, 0, stream>>>(wq, wk, wv, wT);
  qkv_gemm<<<dim3(256, 1, 3), 256, 0, stream>>>(query, key, value, wT, Qws,
                                                Kws, Vtws);
  flash_attn<<<dim3(32, 16), 256, 0, stream>>>(Qws, Kws, Vtws, key_mask, out);
}

// Round 8
// 183.801 us; speedup vs baseline: 1.4674x; 1.4674x over previous
//
#include <hip/hip_runtime.h>

typedef _Float16 f16;
typedef f16 f16x8 __attribute__((ext_vector_type(8)));
typedef f16 f16x4 __attribute__((ext_vector_type(4)));
typedef f16 f16x2 __attribute__((ext_vector_type(2)));
typedef float f32x4 __attribute__((ext_vector_type(4)));
typedef unsigned int u32;

#define MFMA16(a, b, c) __builtin_amdgcn_mfma_f32_16x16x32_f16(a, b, c, 0, 0, 0)

#define BATCH 4
#define NHEADS 8
#define HDIM 64
#define SEQ 2048
#define DIN 512
#define DOUT 512
#define LOG2E 1.44269504f
#define C1 0.18033688f  // 0.125 * log2(e), folded into Q at qkv epilogue

__device__ __forceinline__ void gl_lds16(const void* g, const void* l) {
  __builtin_amdgcn_global_load_lds(
      (const __attribute__((address_space(1))) u32*)g,
      (__attribute__((address_space(3))) u32*)l, 16, 0, 0);
}

__device__ __forceinline__ float fexp2(float x) {
  float r;
  asm("v_exp_f32 %0, %1" : "=v"(r) : "v"(x));
  return r;
}

__device__ __forceinline__ f16x2 pk2(float a, float b) {
  return __builtin_bit_cast(f16x2, __builtin_amdgcn_cvt_pkrtz(a, b));
}

__device__ __forceinline__ f16x4 pk4(float a, float b, float c, float d) {
  f16x2 u0 = pk2(a, b), u1 = pk2(c, d);
  f16x4 r;
  r[0] = u0[0]; r[1] = u0[1]; r[2] = u1[0]; r[3] = u1[1];
  return r;
}

// ---------------------------------------------------------------------------
// prep_w: transpose+cvt weights w[k][n] fp32 -> wT[n][k] f16.
// ---------------------------------------------------------------------------
__global__ __launch_bounds__(256) void prep_w(
    const float* __restrict__ wq, const float* __restrict__ wk,
    const float* __restrict__ wv, f16* __restrict__ wT) {
  __shared__ float tile[64][65];
  const float* w = blockIdx.z == 0 ? wq : (blockIdx.z == 1 ? wk : wv);
  f16* out = wT + (size_t)blockIdx.z * DIN * DOUT;
  int k0 = blockIdx.x * 64, n0 = blockIdx.y * 64;
  int t = threadIdx.x;
  int c = t & 63, rb = t >> 6;
#pragma unroll
  for (int ph = 0; ph < 16; ++ph) {
    int r = ph * 4 + rb;
    tile[r][c] = w[(size_t)(k0 + r) * DOUT + n0 + c];
  }
  __syncthreads();
#pragma unroll
  for (int ph = 0; ph < 16; ++ph) {
    int n = ph * 4 + rb;
    out[(size_t)(n0 + n) * DIN + k0 + c] = (f16)tile[c][n];
  }
}

// ---------------------------------------------------------------------------
// qkv_gemm: R6-verbatim main loop (no reg prefetch — R7 showed it spills).
// ONE new variable vs R6: epilogue restages C through LDS (aliasing As/Bs)
// so every global store is a wave-contiguous >=128B segment.
// grid (256,1,3): m = bx&63, n = bx>>6 (n-partners share an XCD's L2).
// ---------------------------------------------------------------------------
__global__ __launch_bounds__(256, 3) void qkv_gemm(
    const float* __restrict__ xq, const float* __restrict__ xk,
    const float* __restrict__ xv, const f16* __restrict__ wT,
    f16* __restrict__ Qo, f16* __restrict__ Ko, f16* __restrict__ Vt) {
  __shared__ __attribute__((aligned(16))) f16 smem[16384];  // 32 KB
  f16* As = smem;          // 128x64
  f16* Bs = smem + 8192;   // 128x64
  f16* CT = smem;          // epilogue: 128x128 (aliases As+Bs)

  int gemm = blockIdx.z;
  const float* x = gemm == 0 ? xq : (gemm == 1 ? xk : xv);
  const f16* wt = wT + (size_t)gemm * DIN * DOUT;
  int bx = blockIdx.x;
  int m0 = (bx & 63) * 128, n0 = (bx >> 6) * 128;
  int t = threadIdx.x, w = t >> 6, lane = t & 63;
  int lr = lane & 15, lq = lane >> 4;
  int wm = (w >> 1) * 64, wn = (w & 1) * 64;

  // A staging (fp32 -> f16 through regs): 16 threads/row, 8 row-phases.
  int tr = t >> 4, tc = t & 15;
  const float* xg = x + (size_t)(m0 + tr) * DIN + tc * 4;
  int aw[8];
#pragma unroll
  for (int ph = 0; ph < 8; ++ph) {
    int r = tr + 16 * ph;
    int phys = (tc >> 1) ^ (r & 7);
    aw[ph] = r * 64 + phys * 8 + (tc & 1) * 4;
  }

  // B staging via DMA: regions of 8 rows x 128B, XOR chunk swizzle.
  int srow = lane >> 3;
  int schunk = (lane & 7) ^ srow;
  const f16* gb[4];
  const f16* lbb[4];
#pragma unroll
  for (int j = 0; j < 4; ++j) {
    int br = w * 32 + j * 8;
    gb[j] = wt + (size_t)(n0 + br + srow) * DIN + schunk * 8;
    lbb[j] = &Bs[__builtin_amdgcn_readfirstlane(br * 64)];
  }
  int xo0 = ((0 * 4 + lq) ^ (lr & 7)) * 8;
  int xo1 = ((1 * 4 + lq) ^ (lr & 7)) * 8;

  f32x4 zero = {0.f, 0.f, 0.f, 0.f};
  f32x4 acc[4][4];
#pragma unroll
  for (int i = 0; i < 4; ++i)
#pragma unroll
    for (int j = 0; j < 4; ++j) acc[i][j] = zero;

  for (int k0 = 0; k0 < DIN; k0 += 64) {
    __syncthreads();
#pragma unroll
    for (int j = 0; j < 4; ++j) gl_lds16(gb[j] + k0, lbb[j]);
#pragma unroll
    for (int ph = 0; ph < 8; ++ph) {
      float4 a = *(const float4*)(xg + (size_t)ph * 16 * DIN + k0);
      *(f16x4*)&As[aw[ph]] = pk4(a.x, a.y, a.z, a.w);
    }
    __syncthreads();
#pragma unroll
    for (int c = 0; c < 2; ++c) {
      int xo = c ? xo1 : xo0;
      f16x8 xf[4], wf[4];
#pragma unroll
      for (int i = 0; i < 4; ++i)
        xf[i] = *(const f16x8*)&As[(wm + i * 16 + lr) * 64 + xo];
#pragma unroll
      for (int i = 0; i < 4; ++i)
        wf[i] = *(const f16x8*)&Bs[(wn + i * 16 + lr) * 64 + xo];
      if (gemm == 2) {
#pragma unroll
        for (int i = 0; i < 4; ++i)
#pragma unroll
          for (int j = 0; j < 4; ++j)
            acc[i][j] = MFMA16(xf[i], wf[j], acc[i][j]);
      } else {
#pragma unroll
        for (int i = 0; i < 4; ++i)
#pragma unroll
          for (int j = 0; j < 4; ++j)
            acc[i][j] = MFMA16(wf[i], xf[j], acc[i][j]);
      }
    }
  }

  __syncthreads();  // all MFMA reads of As/Bs done before CT overwrite
  int b_ = m0 >> 11;
  int sl = m0 & 2047;

  if (gemm == 2) {
    // D[m=s][n=d], regs = 4 consecutive s.  CT2[d][s_local] (128x128).
    // write: d = wn + j*16 + lr;  s chunk lc = (wm>>3) + i*2 + (lq>>1);
    // phys = lc ^ (d & 15) = lc ^ lr.
#pragma unroll
    for (int i = 0; i < 4; ++i) {
#pragma unroll
      for (int j = 0; j < 4; ++j) {
        int d = wn + j * 16 + lr;
        int lc = (wm >> 3) + i * 2 + (lq >> 1);
        int phys = lc ^ lr;
        *(f16x4*)&CT[d * 128 + phys * 8 + (lq & 1) * 4] =
            pk4(acc[i][j][0], acc[i][j][1], acc[i][j][2], acc[i][j][3]);
      }
    }
    __syncthreads();
    // read: 16 threads per d-row (16B chunks), 8 phases of 16 rows.
    int tid16 = t & 15;
#pragma unroll
    for (int ph = 0; ph < 8; ++ph) {
      int d = ph * 16 + (t >> 4);
      int phys = tid16 ^ (d & 15);
      f16x8 vv = *(const f16x8*)&CT[d * 128 + phys * 8];
      int hgl = (n0 + d) >> 6, dd = (n0 + d) & 63;
      *(f16x8*)&Vt[(((size_t)b_ * NHEADS + hgl) * HDIM + dd) * SEQ + sl +
                   tid16 * 8] = vv;
    }
  } else {
    // swapped: D[m=d][n=s], regs = 4 consecutive d.  CT[s_local][d] (128x128).
    // write: s_local = wm + j*16 + lr;  d chunk lc = (wn>>3) + i*2 + (lq>>1);
    // phys = lc ^ (s_local & 15) = lc ^ lr.
    f16* O = gemm == 0 ? Qo : Ko;
    float sc = gemm == 0 ? C1 : 1.0f;
#pragma unroll
    for (int i = 0; i < 4; ++i) {
#pragma unroll
      for (int j = 0; j < 4; ++j) {
        int s = wm + j * 16 + lr;
        int lc = (wn >> 3) + i * 2 + (lq >> 1);
        int phys = lc ^ lr;
        *(f16x4*)&CT[s * 128 + phys * 8 + (lq & 1) * 4] =
            pk4(acc[i][j][0] * sc, acc[i][j][1] * sc, acc[i][j][2] * sc,
                acc[i][j][3] * sc);
      }
    }
    __syncthreads();
    // read: 8 threads per (s, head-half) = 64 halves; 8 phases of 16 rows.
    int tid8 = t & 7;
    int hh = (t >> 3) & 1;
#pragma unroll
    for (int ph = 0; ph < 8; ++ph) {
      int s = ph * 16 + (t >> 4);
      int lc = hh * 8 + tid8;
      int phys = lc ^ (s & 15);
      f16x8 vv = *(const f16x8*)&CT[s * 128 + phys * 8];
      int hgl = (n0 >> 6) + hh;
      *(f16x8*)&O[(((size_t)b_ * NHEADS + hgl) * SEQ + sl + s) * HDIM +
                  tid8 * 8] = vv;
    }
  }
}

// ---------------------------------------------------------------------------
// flash_attn (R6-verbatim, verified): S^T = K.Q^T.  Q-tile 128 (32/wave as
// 2x16 strips, registers), K-tile 128.  No online max; exp2 domain (Q
// pre-scaled by C1, mask folded via fmaf).  grid(bh=32, qt=16).
// ---------------------------------------------------------------------------
__global__ __launch_bounds__(256, 2) void flash_attn(
    const f16* __restrict__ Q, const f16* __restrict__ K,
    const f16* __restrict__ Vt, const float* __restrict__ mask,
    float* __restrict__ out) {
  __shared__ __attribute__((aligned(16))) f16 Ks[128 * 64];   // [k][d] swizzled
  __shared__ __attribute__((aligned(16))) f16 Vs[64 * 128];   // [d][k] swizzled
  __shared__ __attribute__((aligned(16))) f16 Ps[128 * 136];  // [q][k] padded

  int bh = blockIdx.x, q0 = blockIdx.y * 128;
  int b = bh >> 3, h = bh & 7;
  int t = threadIdx.x, w = t >> 6, lane = t & 63;
  int lr = lane & 15, lq = lane >> 4;

  const f16* Qg = Q + (size_t)bh * SEQ * HDIM;
  const f16* Kg = K + (size_t)bh * SEQ * HDIM;
  const f16* Vg = Vt + (size_t)bh * HDIM * SEQ;
  const float* mg = mask + (size_t)b * SEQ;

  // Q fragments in registers: wave rows w*32 + u*16 + lr
  f16x8 qf[2][2];
#pragma unroll
  for (int u = 0; u < 2; ++u)
#pragma unroll
    for (int c = 0; c < 2; ++c)
      qf[u][c] = *(const f16x8*)(Qg +
                                 (size_t)(q0 + w * 32 + u * 16 + lr) * HDIM +
                                 c * 32 + lq * 8);

  // K staging: regions of 8 rows x 128B
  int krow = lane >> 3;
  int kchunk = (lane & 7) ^ krow;
  const f16* gk[4];
  const f16* gv[4];
  const f16* lk[4];
  const f16* lv[4];
#pragma unroll
  for (int j = 0; j < 4; ++j) {
    int kbr = w * 32 + j * 8;
    gk[j] = Kg + (size_t)(kbr + krow) * HDIM + kchunk * 8;
    lk[j] = &Ks[__builtin_amdgcn_readfirstlane(kbr * 64)];
    int vbr = w * 16 + j * 4;
    int vchunk = (lane & 15) ^ (j * 4 + lq);
    gv[j] = Vg + (size_t)(vbr + lq) * SEQ + vchunk * 8;
    lv[j] = &Vs[__builtin_amdgcn_readfirstlane(vbr * 128)];
  }
  int xk0 = ((0 * 4 + lq) ^ (lr & 7)) * 8;
  int xk1 = ((1 * 4 + lq) ^ (lr & 7)) * 8;

  f32x4 zero = {0.f, 0.f, 0.f, 0.f};
  f32x4 acc[2][4];
#pragma unroll
  for (int u = 0; u < 2; ++u)
#pragma unroll
    for (int i = 0; i < 4; ++i) acc[u][i] = zero;
  float lsum[2] = {0.f, 0.f};

  for (int k0 = 0; k0 < SEQ; k0 += 128) {
    __syncthreads();
#pragma unroll
    for (int j = 0; j < 4; ++j) {
      gl_lds16(gk[j] + (size_t)k0 * HDIM, lk[j]);
      gl_lds16(gv[j] + k0, lv[j]);
    }
    __syncthreads();

    // ---- S^T = K Q^T : per strip u, D[m=k][n=q]; q=lane&15, k=lq*4+reg
    f32x4 s[2][8];
#pragma unroll
    for (int nt = 0; nt < 8; ++nt) {
      f16x8 kf0 = *(const f16x8*)&Ks[(nt * 16 + lr) * 64 + xk0];
      f16x8 kf1 = *(const f16x8*)&Ks[(nt * 16 + lr) * 64 + xk1];
      s[0][nt] = MFMA16(kf0, qf[0][0], zero);
      s[0][nt] = MFMA16(kf1, qf[0][1], s[0][nt]);
      s[1][nt] = MFMA16(kf0, qf[1][0], zero);
      s[1][nt] = MFMA16(kf1, qf[1][1], s[1][nt]);
    }

    // ---- p = exp2(s + mask*log2e); accumulate l per lane; pack -> Ps
#pragma unroll
    for (int nt = 0; nt < 8; ++nt) {
      float4 mk = *(const float4*)(mg + k0 + nt * 16 + lq * 4);
#pragma unroll
      for (int u = 0; u < 2; ++u) {
        float p0 = fexp2(fmaf(mk.x, LOG2E, s[u][nt][0]));
        float p1 = fexp2(fmaf(mk.y, LOG2E, s[u][nt][1]));
        float p2 = fexp2(fmaf(mk.z, LOG2E, s[u][nt][2]));
        float p3 = fexp2(fmaf(mk.w, LOG2E, s[u][nt][3]));
        lsum[u] += (p0 + p1) + (p2 + p3);
        *(f16x4*)&Ps[(w * 32 + u * 16 + lr) * 136 + nt * 16 + lq * 4] =
            pk4(p0, p1, p2, p3);
      }
    }

    // ---- O += P V : ap per strip (own rows), bv shared across strips
#pragma unroll
    for (int ks = 0; ks < 4; ++ks) {
      f16x8 ap0 = *(const f16x8*)&Ps[(w * 32 + lr) * 136 + ks * 32 + lq * 8];
      f16x8 ap1 =
          *(const f16x8*)&Ps[(w * 32 + 16 + lr) * 136 + ks * 32 + lq * 8];
#pragma unroll
      for (int dt = 0; dt < 4; ++dt) {
        f16x8 bv = *(const f16x8*)&Vs[(dt * 16 + lr) * 128 +
                                      (((ks * 4 + lq) ^ lr) * 8)];
        acc[0][dt] = MFMA16(ap0, bv, acc[0][dt]);
        acc[1][dt] = MFMA16(ap1, bv, acc[1][dt]);
      }
    }
  }

  // epilogue: l reduction + normalize + store
#pragma unroll
  for (int u = 0; u < 2; ++u) {
    float l = lsum[u];
    l += __shfl_xor(l, 16);
    l += __shfl_xor(l, 32);
    float inv = 1.f / l;
    float iv[4];
#pragma unroll
    for (int r = 0; r < 4; ++r) iv[r] = __shfl(inv, lq * 4 + r);
#pragma unroll
    for (int dt = 0; dt < 4; ++dt) {
#pragma unroll
      for (int r = 0; r < 4; ++r) {
        int q = q0 + w * 32 + u * 16 + lq * 4 + r;
        int d = h * HDIM + dt * 16 + lr;
        out[((size_t)b * SEQ + q) * DOUT + d] = acc[u][dt][r] * iv[r];
      }
    }
  }
}

// ---------------------------------------------------------------------------
extern "C" void kernel_launch(void* const* d_in, const int* in_sizes, int n_in,
                              void* d_out, int out_size, void* d_ws,
                              size_t ws_size, hipStream_t stream) {
  const float* key = (const float*)d_in[0];
  const float* key_mask = (const float*)d_in[1];
  const float* query = (const float*)d_in[2];
  const float* value = (const float*)d_in[3];
  const float* wq = (const float*)d_in[4];
  const float* wk = (const float*)d_in[5];
  const float* wv = (const float*)d_in[6];
  float* out = (float*)d_out;

  char* ws = (char*)d_ws;
  f16* Qws = (f16*)(ws);              //  8.39 MB
  f16* Kws = (f16*)(ws + 8388608);    //  8.39 MB
  f16* Vtws = (f16*)(ws + 16777216);  //  8.39 MB
  f16* wT = (f16*)(ws + 25165824);    //  1.57 MB (total ~26.7 MB)

  prep_w<<<dim3(8, 8, 3), 256, 0, stream>>>(wq, wk, wv, wT);
  qkv_gemm<<<dim3(256, 1, 3), 256, 0, stream>>>(query, key, value, wT, Qws,
                                                Kws, Vtws);
  flash_attn<<<dim3(32, 16), 256, 0, stream>>>(Qws, Kws, Vtws, key_mask, out);
}